// Round 14
// baseline (515.188 us; speedup 1.0000x reference)
//
#include <hip/hip_runtime.h>
#include <hip/hip_bf16.h>

// QuantizedLinear: y[M,N] = x[M,K] . W[N,K]^T + bias ; W = int4 * groupscale(G=128)
// Round 13: R12's 128x128 i8 2-blocks/CU kernel, inner loop re-pipelined:
// next tile's B ds_reads INTERLEAVED inside the MFMA cluster ({2 MFMA,1 read}x8,
// sched_group_barrier-pinned), A-reads after cluster, 1 barrier/tile, lead-2
// WAITV(0) (counted-equivalent). bF double-set keeps unified regs at 128 (tier).

typedef __bf16 bf16_t;
typedef __bf16 bf16x8 __attribute__((ext_vector_type(8)));
typedef float f32x4 __attribute__((ext_vector_type(4)));
typedef int ix4 __attribute__((ext_vector_type(4)));
typedef __attribute__((address_space(3))) unsigned char lds_byte;
typedef __attribute__((address_space(1))) unsigned char gmem_byte;

// ---------------- fused pre-pass: blocks [0,M) = x rows; [M, M+O) = W rows ----------------
__global__ void prep_kernel(const float* __restrict__ x, int* __restrict__ xq,
                            float* __restrict__ sx,
                            const int* __restrict__ qw, const float* __restrict__ sc,
                            float* __restrict__ tw, int* __restrict__ wq,
                            int M, int I, int NG) {
  __shared__ float red[256];
  const int b = blockIdx.x;
  const int t = threadIdx.x;
  if (b < M) {
    const float* row = x + (size_t)b * I;
    float mx = 0.f;
    for (int c = t * 4; c < I; c += 1024) {
      const float4 f = *reinterpret_cast<const float4*>(row + c);
      mx = fmaxf(mx, fmaxf(fmaxf(fabsf(f.x), fabsf(f.y)), fmaxf(fabsf(f.z), fabsf(f.w))));
    }
    red[t] = mx;
    __syncthreads();
#pragma unroll
    for (int s = 128; s > 0; s >>= 1) {
      if (t < s) red[t] = fmaxf(red[t], red[t + s]);
      __syncthreads();
    }
    const float rm = fmaxf(red[0], 1e-30f);
    if (t == 0) sx[b] = rm * (1.f / 127.f);
    const float inv = 127.f / rm;
    int* orow = xq + (size_t)b * (I >> 2);
    for (int c = t * 4; c < I; c += 1024) {
      const float4 f = *reinterpret_cast<const float4*>(row + c);
      const int b0 = (int)rintf(f.x * inv), b1 = (int)rintf(f.y * inv);
      const int b2 = (int)rintf(f.z * inv), b3 = (int)rintf(f.w * inv);
      orow[c >> 2] = (b0 & 255) | ((b1 & 255) << 8) | ((b2 & 255) << 16) | (b3 << 24);
    }
  } else {
    const int n = b - M;
    const float* srow = sc + (size_t)n * NG;
    float mx = 0.f;
    for (int g = t; g < NG; g += 256) mx = fmaxf(mx, srow[g]);
    red[t] = mx;
    __syncthreads();
#pragma unroll
    for (int s = 128; s > 0; s >>= 1) {
      if (t < s) red[t] = fmaxf(red[t], red[t + s]);
      __syncthreads();
    }
    const float tn = fmaxf(red[0], 1e-30f) * (8.f / 127.f);
    if (t == 0) tw[n] = tn;
    const float itn = 1.f / tn;
    const int* qrow = qw + (size_t)n * I;
    int* orow = wq + (size_t)n * (I >> 2);
    for (int k0 = t * 16; k0 < I; k0 += 4096) {
      const float f = srow[k0 >> 7] * itn;
      const int4* p = reinterpret_cast<const int4*>(qrow + k0);
      const int4 q0 = p[0], q1 = p[1], q2 = p[2], q3 = p[3];
      int v[16];
      v[0] = (int)rintf((float)q0.x * f); v[1] = (int)rintf((float)q0.y * f);
      v[2] = (int)rintf((float)q0.z * f); v[3] = (int)rintf((float)q0.w * f);
      v[4] = (int)rintf((float)q1.x * f); v[5] = (int)rintf((float)q1.y * f);
      v[6] = (int)rintf((float)q1.z * f); v[7] = (int)rintf((float)q1.w * f);
      v[8] = (int)rintf((float)q2.x * f); v[9] = (int)rintf((float)q2.y * f);
      v[10] = (int)rintf((float)q2.z * f); v[11] = (int)rintf((float)q2.w * f);
      v[12] = (int)rintf((float)q3.x * f); v[13] = (int)rintf((float)q3.y * f);
      v[14] = (int)rintf((float)q3.z * f); v[15] = (int)rintf((float)q3.w * f);
      int4 o;
      o.x = (v[0] & 255) | ((v[1] & 255) << 8) | ((v[2] & 255) << 16) | (v[3] << 24);
      o.y = (v[4] & 255) | ((v[5] & 255) << 8) | ((v[6] & 255) << 16) | (v[7] << 24);
      o.z = (v[8] & 255) | ((v[9] & 255) << 8) | ((v[10] & 255) << 16) | (v[11] << 24);
      o.w = (v[12] & 255) | ((v[13] & 255) << 8) | ((v[14] & 255) << 16) | (v[15] << 24);
      *reinterpret_cast<int4*>(orow + (k0 >> 2)) = o;
    }
  }
}

// =================== 128x128 8-wave i8 GEMM, 2 blocks/CU, interleaved pipeline ===================
// LDS 64KB: buf0.A @0, buf0.B @16K, buf1.A @32K, buf1.B @48K. Tile = 128 rows x
// 128B (128 i8 of K); XOR swizzle 16B-slot ^= (row&7) (verified conflict-free).
// Waves: 4M x 2N, wave-tile 32x64. Frags: aF (single set), bE/bO (double set).
// Body(t): WAITV(0) [drains t+1, staged 1 body ago]; BAR [publish t+1 + WAR
// fence for STG below]; STG(buf[t&1], t+2); { 16 MFMA(t) interleaved with 8
// ds_read B(t+1) } ; 4 ds_read A(t+1); WAITL(0).
// WAR: tile t's frags were read in body(t-1), drained by its WAITL(0), and
// body(t)'s BAR orders that before STG(t+2) overwrite. RAW: reads of t+1 come
// after WAITV(0)+BAR publish. FIFO: exactly one 4-load stage in flight at each
// body top -> WAITV(0) == counted drain of loads issued ~1000 cyc earlier.

#define WAITV(n) asm volatile("s_waitcnt vmcnt(" #n ")" ::: "memory")
#define WAITL(n) asm volatile("s_waitcnt lgkmcnt(" #n ")" ::: "memory")
#define BAR() __builtin_amdgcn_s_barrier()
#define SETP(n) __builtin_amdgcn_s_setprio(n)
#define SGB __builtin_amdgcn_sched_group_barrier

#define RD_A(DB) do { \
  _Pragma("unroll") \
  for (int m_ = 0; m_ < 2; ++m_) { \
    aF[m_][0] = *reinterpret_cast<const ix4*>(&ldsb[(DB) + aRd + (unsigned)(m_ * 16) * 128u + ks0]); \
    aF[m_][1] = *reinterpret_cast<const ix4*>(&ldsb[(DB) + aRd + (unsigned)(m_ * 16) * 128u + ks1]); \
  } \
} while (0)

// interleaved cluster: 16 MFMA on (aF, BC) + 8 ds_reads of next-tile B into BN
// from dbuf DBN. Pattern {2 MFMA, 1 DS_READ} x8, pinned by sched_group_barrier.
#define CLUSTER(BC, BN, DBN) do { \
  _Pragma("unroll") \
  for (int p_ = 0; p_ < 8; ++p_) { \
    const int m_ = p_ >> 2, n_ = p_ & 3; \
    acc[m_][n_] = __builtin_amdgcn_mfma_i32_16x16x64_i8(aF[m_][0], BC[n_][0], acc[m_][n_], 0, 0, 0); \
    acc[m_][n_] = __builtin_amdgcn_mfma_i32_16x16x64_i8(aF[m_][1], BC[n_][1], acc[m_][n_], 0, 0, 0); \
    const int rn_ = p_ >> 1, rs_ = p_ & 1; \
    BN[rn_][rs_] = *reinterpret_cast<const ix4*>( \
      &ldsb[(DBN) + 16384u + bRd + (unsigned)(rn_ * 16) * 128u + (rs_ ? ks1 : ks0)]); \
  } \
  _Pragma("unroll") \
  for (int p_ = 0; p_ < 8; ++p_) { SGB(0x8, 2, 0); SGB(0x100, 1, 0); } \
} while (0)

// final cluster: MFMA only
#define CLUSTER_LAST(BC) do { \
  _Pragma("unroll") \
  for (int p_ = 0; p_ < 8; ++p_) { \
    const int m_ = p_ >> 2, n_ = p_ & 3; \
    acc[m_][n_] = __builtin_amdgcn_mfma_i32_16x16x64_i8(aF[m_][0], BC[n_][0], acc[m_][n_], 0, 0, 0); \
    acc[m_][n_] = __builtin_amdgcn_mfma_i32_16x16x64_i8(aF[m_][1], BC[n_][1], acc[m_][n_], 0, 0, 0); \
  } \
} while (0)

#define STG(BASE, P, tau) do { \
  __builtin_amdgcn_global_load_lds((const gmem_byte*)((P) + (size_t)(tau) * 128), \
                                   (lds_byte*)&ldsb[(BASE) + wOff], 16, 0, 0); \
  __builtin_amdgcn_global_load_lds((const gmem_byte*)((P) + (size_t)64 * K + (size_t)(tau) * 128), \
                                   (lds_byte*)&ldsb[(BASE) + 8192u + wOff], 16, 0, 0); \
} while (0)

__launch_bounds__(512, 4)
__global__ void gemm128_i8_kernel(const char* __restrict__ A, const char* __restrict__ B,
                                  const float* __restrict__ sx, const float* __restrict__ tw,
                                  const float* __restrict__ bias, float* __restrict__ C,
                                  int M, int N, int K) {
  __shared__ __align__(16) unsigned char ldsb[65536];

  const int tid = threadIdx.x;
  const int lane = tid & 63;
  const int w = tid >> 6;       // 0..7
  const int wr = w >> 1;        // m-quarter 0..3
  const int wc = w & 1;         // n-half 0..1

  // T1: bijective XCD swizzle (MT % 8 == 0 path; MT = M/128).
  const int MT = M >> 7;
  int mt, nt;
  const int bid = blockIdx.x;
  if ((MT & 7) == 0) {
    const int xcd = bid & 7, idx = bid >> 3;
    const int mpx = MT >> 3;
    nt = idx / mpx;
    mt = xcd * mpx + (idx - nt * mpx);
  } else {
    mt = bid % MT;
    nt = bid / MT;
  }
  const int m0 = mt << 7, n0 = nt << 7;

  // ---- staging addressing (linear LDS dest, pre-swizzled global source) ----
  const int srow8 = lane >> 3;
  const int scol16 = (lane & 7) ^ (srow8 & 7);
  const char* aP = A + (size_t)(m0 + w * 8 + srow8) * K + scol16 * 16;
  const char* bP = B + (size_t)(n0 + w * 8 + srow8) * K + scol16 * 16;
  const unsigned wOff = (unsigned)w * 1024u;

  // ---- fragment read addressing (verified swizzle fold) ----
  const unsigned fr = lane & 15;
  const unsigned hi16 = (unsigned)lane >> 4;
  const unsigned sw_ = (fr & 7u) << 4;
  const unsigned ks0 = (hi16 * 16u) ^ sw_;          // k-bytes 0..63 chunk
  const unsigned ks1 = (64u + hi16 * 16u) ^ sw_;    // k-bytes 64..127 chunk
  const unsigned aRd = ((unsigned)(wr * 32) + fr) * 128u;   // + msub*16*128
  const unsigned bRd = ((unsigned)(wc * 64) + fr) * 128u;   // + nsub*16*128

  ix4 acc[2][4];
#pragma unroll
  for (int i = 0; i < 2; ++i)
#pragma unroll
    for (int j = 0; j < 4; ++j) acc[i][j] = (ix4){0, 0, 0, 0};

  ix4 aF[2][2], bE[4][2], bO[4][2];

  const int NITER = K >> 7;  // K/128 tiles; even, >=4 guarded at launch

  // ---- prologue: tile0 -> buf0, tile1 -> buf1; read tile0 frags ----
  STG(0u, aP, 0); STG(16384u, bP, 0);
  STG(32768u, aP, 1); STG(49152u, bP, 1);
  WAITV(4);   // tile0 landed; tile1 in flight
  BAR();
  {
#pragma unroll
    for (int p_ = 0; p_ < 8; ++p_) {
      const int rn_ = p_ >> 1, rs_ = p_ & 1;
      bE[rn_][rs_] = *reinterpret_cast<const ix4*>(
        &ldsb[16384u + bRd + (unsigned)(rn_ * 16) * 128u + (rs_ ? ks1 : ks0)]);
    }
  }
  RD_A(0u);
  WAITL(0);

  for (int it = 0; it < (NITER >> 1) - 1; ++it) {
    const int t = 2 * it;
    // ---- even body: tile t (buf0, bE); prefetch B(t+1)->bO from buf1 ----
    WAITV(0);                  // drains tile t+1's stage (issued 1 body ago)
    BAR();                     // publish t+1; WAR fence for STG below
    STG(0u, aP, t + 2); STG(16384u, bP, t + 2);
    SETP(1); CLUSTER(bE, bO, 32768u); SETP(0);
    RD_A(32768u);              // A(t+1)
    WAITL(0);
    // ---- odd body: tile t+1 (buf1, bO); prefetch B(t+2)->bE from buf0 ----
    WAITV(0);                  // drains tile t+2's stage
    BAR();
    STG(32768u, aP, t + 3); STG(49152u, bP, t + 3);
    SETP(1); CLUSTER(bO, bE, 0u); SETP(0);
    RD_A(0u);                  // A(t+2)
    WAITL(0);
  }
  // ---- tail: tiles NITER-2 (buf0, bE), NITER-1 (buf1, bO); no staging ----
  {
    WAITV(0);                  // drains tile NITER-1's stage
    BAR();
    SETP(1); CLUSTER(bE, bO, 32768u); SETP(0);
    RD_A(32768u);
    WAITL(0);
    SETP(1); CLUSTER_LAST(bO); SETP(0);
  }

  // ---- epilogue: y = sx[row]*tw[n]*acc + bias ----
  const int row0 = m0 + wr * 32 + ((lane >> 4) << 2);
  const int col0 = n0 + wc * 64 + (lane & 15);
  float sxc[2][4];
#pragma unroll
  for (int m_ = 0; m_ < 2; ++m_) {
    const int rbase = row0 + m_ * 16;
#pragma unroll
    for (int r = 0; r < 4; ++r) sxc[m_][r] = sx[rbase + r];
  }
#pragma unroll
  for (int n_ = 0; n_ < 4; ++n_) {
    const int n = col0 + n_ * 16;
    const float tn = tw[n];
    const float bv = bias[n];
#pragma unroll
    for (int m_ = 0; m_ < 2; ++m_) {
      const int rbase = row0 + m_ * 16;
#pragma unroll
      for (int r = 0; r < 4; ++r)
        C[(size_t)(rbase + r) * N + n] = sxc[m_][r] * tn * (float)acc[m_][n_][r] + bv;
    }
  }
}

// ---------------- fallback path (non-conforming shapes): bf16 two-pass ----------------
__global__ void cvt_x_kernel(const float* __restrict__ x, bf16_t* __restrict__ xb, long n8) {
  const long stride = (long)gridDim.x * blockDim.x;
  for (long i = (long)blockIdx.x * blockDim.x + threadIdx.x; i < n8; i += stride) {
    const float4* p = reinterpret_cast<const float4*>(x + i * 8);
    const float4 f0 = p[0];
    const float4 f1 = p[1];
    bf16x8 o;
    o[0] = (bf16_t)f0.x; o[1] = (bf16_t)f0.y; o[2] = (bf16_t)f0.z; o[3] = (bf16_t)f0.w;
    o[4] = (bf16_t)f1.x; o[5] = (bf16_t)f1.y; o[6] = (bf16_t)f1.z; o[7] = (bf16_t)f1.w;
    *reinterpret_cast<bf16x8*>(xb + i * 8) = o;
  }
}

__global__ void deq_w_kernel(const int* __restrict__ qw, const float* __restrict__ sc,
                             bf16_t* __restrict__ wb, int I, int G) {
  const int n = blockIdx.y;
  const int kb = blockIdx.x * blockDim.x + threadIdx.x;
  const int k = kb * 8;
  if (k >= I) return;
  const float s = sc[(size_t)n * (I / G) + k / G];
  const int4* qp = reinterpret_cast<const int4*>(qw + (size_t)n * I + k);
  const int4 q0 = qp[0];
  const int4 q1 = qp[1];
  bf16x8 o;
  o[0] = (bf16_t)((float)q0.x * s);
  o[1] = (bf16_t)((float)q0.y * s);
  o[2] = (bf16_t)((float)q0.z * s);
  o[3] = (bf16_t)((float)q0.w * s);
  o[4] = (bf16_t)((float)q1.x * s);
  o[5] = (bf16_t)((float)q1.y * s);
  o[6] = (bf16_t)((float)q1.z * s);
  o[7] = (bf16_t)((float)q1.w * s);
  *reinterpret_cast<bf16x8*>(wb + (size_t)n * I + k) = o;
}

#define BM 128
#define BK 32
__launch_bounds__(256)
__global__ void gemm_bt_kernel(const bf16_t* __restrict__ A, const bf16_t* __restrict__ B,
                               const float* __restrict__ bias, float* __restrict__ C,
                               int M, int N, int K) {
  __shared__ __align__(16) bf16_t As[2][BM * BK];
  __shared__ __align__(16) bf16_t Bs[2][BM * BK];
  const int tid = threadIdx.x;
  const int lane = tid & 63;
  const int w = tid >> 6;
  const int wr = w >> 1;
  const int wc = w & 1;
  const int m0 = blockIdx.y * BM;
  const int n0 = blockIdx.x * BM;
  const int srow = lane >> 2;
  const int schunk = lane & 3;
  f32x4 acc[4][4];
  const f32x4 zero = {0.f, 0.f, 0.f, 0.f};
#pragma unroll
  for (int i = 0; i < 4; ++i)
#pragma unroll
    for (int j = 0; j < 4; ++j) acc[i][j] = zero;
  const int nt = K / BK;
  auto stage = [&](int t, int buf) {
    const int k0 = t * BK;
#pragma unroll
    for (int j = 0; j < 2; ++j) {
      const int row = w * 32 + j * 16;
      const bf16_t* ga = A + (size_t)(m0 + row + srow) * K + k0 + schunk * 8;
      __builtin_amdgcn_global_load_lds((const gmem_byte*)ga, (lds_byte*)&As[buf][row * BK], 16, 0, 0);
      const bf16_t* gb = B + (size_t)(n0 + row + srow) * K + k0 + schunk * 8;
      __builtin_amdgcn_global_load_lds((const gmem_byte*)gb, (lds_byte*)&Bs[buf][row * BK], 16, 0, 0);
    }
  };
  auto compute = [&](int buf) {
    bf16x8 af[4], bfr[4];
    const int fr2 = lane & 15;
    const int kc = (lane >> 4) * 8;
#pragma unroll
    for (int i = 0; i < 4; ++i) {
      af[i] = *reinterpret_cast<const bf16x8*>(&As[buf][(wr * 64 + i * 16 + fr2) * BK + kc]);
      bfr[i] = *reinterpret_cast<const bf16x8*>(&Bs[buf][(wc * 64 + i * 16 + fr2) * BK + kc]);
    }
#pragma unroll
    for (int i = 0; i < 4; ++i)
#pragma unroll
      for (int j = 0; j < 4; ++j)
        acc[i][j] = __builtin_amdgcn_mfma_f32_16x16x32_bf16(af[i], bfr[j], acc[i][j], 0, 0, 0);
  };
  stage(0, 0);
  __syncthreads();
  int cur = 0;
  for (int t = 0; t < nt - 1; ++t) {
    stage(t + 1, cur ^ 1);
    compute(cur);
    __syncthreads();
    cur ^= 1;
  }
  compute(cur);
#pragma unroll
  for (int j = 0; j < 4; ++j) {
    const int n = n0 + wc * 64 + j * 16 + (lane & 15);
    const float bv = bias[n];
#pragma unroll
    for (int i = 0; i < 4; ++i) {
      const int mbase = m0 + wr * 64 + i * 16 + (lane >> 4) * 4;
#pragma unroll
      for (int r = 0; r < 4; ++r)
        C[(size_t)(mbase + r) * N + n] = acc[i][j][r] + bv;
    }
  }
}

extern "C" void kernel_launch(void* const* d_in, const int* in_sizes, int n_in,
                              void* d_out, int out_size, void* d_ws, size_t ws_size,
                              hipStream_t stream) {
  const float* x = (const float*)d_in[0];
  const int* qw = (const int*)d_in[1];
  const float* sc = (const float*)d_in[2];
  const float* bias = (const float*)d_in[3];
  float* out = (float*)d_out;

  const long O = in_sizes[3];
  const long I = in_sizes[1] / O;        // 4096
  const long M = in_sizes[0] / I;        // 8192
  const long G = I / (in_sizes[2] / O);  // 128
  const long NG = I / G;

  const size_t i8need = (size_t)(M + O) * I + 4 * (size_t)(M + O);
  const long NITER = I >> 7;
  const bool i8ok = ((M & 127) == 0) && ((O & 127) == 0) && ((I & 127) == 0) &&
                    (G == 128) && (NITER >= 4) && ((NITER & 1) == 0) &&
                    (ws_size >= i8need);
  if (i8ok) {
    char* xq = (char*)d_ws;
    char* wq = xq + (size_t)M * I;
    float* sx = (float*)(wq + (size_t)O * I);
    float* tw = sx + M;
    prep_kernel<<<(unsigned)(M + O), 256, 0, stream>>>(x, (int*)xq, sx, qw, sc, tw,
                                                       (int*)wq, (int)M, (int)I, (int)NG);
    const int nwg = (int)((M >> 7) * (O >> 7));
    gemm128_i8_kernel<<<nwg, 512, 0, stream>>>(xq, wq, sx, tw, bias, out, (int)M, (int)O, (int)I);
  } else {
    bf16_t* xb = (bf16_t*)d_ws;
    bf16_t* wb = xb + (size_t)M * I;
    if (ws_size < (size_t)(M + O) * I * sizeof(bf16_t)) return;
    cvt_x_kernel<<<2048, 256, 0, stream>>>(x, xb, M * I / 8);
    dim3 dgrid((unsigned)((I / 8 + 255) / 256), (unsigned)O);
    deq_w_kernel<<<dgrid, 256, 0, stream>>>(qw, sc, wb, (int)I, (int)G);
    dim3 ggrid((unsigned)(O / BM), (unsigned)(M / BM));
    gemm_bt_kernel<<<ggrid, 256, 0, stream>>>(xb, wb, bias, out, (int)M, (int)O, (int)I);
  }
}

// Round 15
// 493.868 us; speedup vs baseline: 1.0432x; 1.0432x over previous
//
#include <hip/hip_runtime.h>
#include <hip/hip_bf16.h>

// QuantizedLinear: y[M,N] = x[M,K] . W[N,K]^T + bias ; W = int4 * groupscale(G=128)
// Round 14: R12's proven 2-blocks/CU antiphase structure, wave-tile enlarged to
// 64x64 (4-wave 256-thread blocks, 128x128 tile) to cut LDS fragment-read
// traffic 17.3GB -> 11.5GB (the measured bound). No interleave, no SGB (R13
// regressed). Same verified swizzle/row-geometry/counted-vmcnt discipline.

typedef __bf16 bf16_t;
typedef __bf16 bf16x8 __attribute__((ext_vector_type(8)));
typedef float f32x4 __attribute__((ext_vector_type(4)));
typedef int ix4 __attribute__((ext_vector_type(4)));
typedef __attribute__((address_space(3))) unsigned char lds_byte;
typedef __attribute__((address_space(1))) unsigned char gmem_byte;

// ---------------- fused pre-pass: blocks [0,M) = x rows; [M, M+O) = W rows ----------------
__global__ void prep_kernel(const float* __restrict__ x, int* __restrict__ xq,
                            float* __restrict__ sx,
                            const int* __restrict__ qw, const float* __restrict__ sc,
                            float* __restrict__ tw, int* __restrict__ wq,
                            int M, int I, int NG) {
  __shared__ float red[256];
  const int b = blockIdx.x;
  const int t = threadIdx.x;
  if (b < M) {
    const float* row = x + (size_t)b * I;
    float mx = 0.f;
    for (int c = t * 4; c < I; c += 1024) {
      const float4 f = *reinterpret_cast<const float4*>(row + c);
      mx = fmaxf(mx, fmaxf(fmaxf(fabsf(f.x), fabsf(f.y)), fmaxf(fabsf(f.z), fabsf(f.w))));
    }
    red[t] = mx;
    __syncthreads();
#pragma unroll
    for (int s = 128; s > 0; s >>= 1) {
      if (t < s) red[t] = fmaxf(red[t], red[t + s]);
      __syncthreads();
    }
    const float rm = fmaxf(red[0], 1e-30f);
    if (t == 0) sx[b] = rm * (1.f / 127.f);
    const float inv = 127.f / rm;
    int* orow = xq + (size_t)b * (I >> 2);
    for (int c = t * 4; c < I; c += 1024) {
      const float4 f = *reinterpret_cast<const float4*>(row + c);
      const int b0 = (int)rintf(f.x * inv), b1 = (int)rintf(f.y * inv);
      const int b2 = (int)rintf(f.z * inv), b3 = (int)rintf(f.w * inv);
      orow[c >> 2] = (b0 & 255) | ((b1 & 255) << 8) | ((b2 & 255) << 16) | (b3 << 24);
    }
  } else {
    const int n = b - M;
    const float* srow = sc + (size_t)n * NG;
    float mx = 0.f;
    for (int g = t; g < NG; g += 256) mx = fmaxf(mx, srow[g]);
    red[t] = mx;
    __syncthreads();
#pragma unroll
    for (int s = 128; s > 0; s >>= 1) {
      if (t < s) red[t] = fmaxf(red[t], red[t + s]);
      __syncthreads();
    }
    const float tn = fmaxf(red[0], 1e-30f) * (8.f / 127.f);
    if (t == 0) tw[n] = tn;
    const float itn = 1.f / tn;
    const int* qrow = qw + (size_t)n * I;
    int* orow = wq + (size_t)n * (I >> 2);
    for (int k0 = t * 16; k0 < I; k0 += 4096) {
      const float f = srow[k0 >> 7] * itn;
      const int4* p = reinterpret_cast<const int4*>(qrow + k0);
      const int4 q0 = p[0], q1 = p[1], q2 = p[2], q3 = p[3];
      int v[16];
      v[0] = (int)rintf((float)q0.x * f); v[1] = (int)rintf((float)q0.y * f);
      v[2] = (int)rintf((float)q0.z * f); v[3] = (int)rintf((float)q0.w * f);
      v[4] = (int)rintf((float)q1.x * f); v[5] = (int)rintf((float)q1.y * f);
      v[6] = (int)rintf((float)q1.z * f); v[7] = (int)rintf((float)q1.w * f);
      v[8] = (int)rintf((float)q2.x * f); v[9] = (int)rintf((float)q2.y * f);
      v[10] = (int)rintf((float)q2.z * f); v[11] = (int)rintf((float)q2.w * f);
      v[12] = (int)rintf((float)q3.x * f); v[13] = (int)rintf((float)q3.y * f);
      v[14] = (int)rintf((float)q3.z * f); v[15] = (int)rintf((float)q3.w * f);
      int4 o;
      o.x = (v[0] & 255) | ((v[1] & 255) << 8) | ((v[2] & 255) << 16) | (v[3] << 24);
      o.y = (v[4] & 255) | ((v[5] & 255) << 8) | ((v[6] & 255) << 16) | (v[7] << 24);
      o.z = (v[8] & 255) | ((v[9] & 255) << 8) | ((v[10] & 255) << 16) | (v[11] << 24);
      o.w = (v[12] & 255) | ((v[13] & 255) << 8) | ((v[14] & 255) << 16) | (v[15] << 24);
      *reinterpret_cast<int4*>(orow + (k0 >> 2)) = o;
    }
  }
}

// =================== 128x128 4-wave i8 GEMM, 2 blocks/CU, 64x64 wave-tile ===================
// LDS 64KB: buf0.A @0, buf0.B @16K, buf1.A @32K, buf1.B @48K. Tile = 128 rows x
// 128B (128 i8 of K); XOR swizzle 16B-slot ^= (row&7) (verified conflict-free).
// Waves: 2M x 2N, wave-tile 64x64 -> acc[4][4] (64 i32), aF[4][2], bF[4][2]
// (16 ds_reads -> 32 MFMA: OPS/LDS-byte 85 vs 42.7 in R12).
// Body(t, buf): RD_T 16x b128; WAITL(0); BAR [reads drained -> WAR fence];
// STG(buf, t+2) [8 loads]; MM 32x; WAITV(8) [drains t+1]; BAR [publish t+1].
// FIFO: outstanding at WAITV(8) = t+1(8) + t+2(8) = 16 -> leaves 8 = drains t+1.

#define WAITV(n) asm volatile("s_waitcnt vmcnt(" #n ")" ::: "memory")
#define WAITL(n) asm volatile("s_waitcnt lgkmcnt(" #n ")" ::: "memory")
#define BAR() __builtin_amdgcn_s_barrier()
#define SETP(n) __builtin_amdgcn_s_setprio(n)

// read full fragment set for the tile in dbuf DB (A @DB, B @DB+16K)
#define RD_T(DB) do { \
  _Pragma("unroll") \
  for (int m_ = 0; m_ < 4; ++m_) { \
    aF[m_][0] = *reinterpret_cast<const ix4*>(&ldsb[(DB) + aRd + (unsigned)(m_ * 16) * 128u + ks0]); \
    aF[m_][1] = *reinterpret_cast<const ix4*>(&ldsb[(DB) + aRd + (unsigned)(m_ * 16) * 128u + ks1]); \
  } \
  _Pragma("unroll") \
  for (int n_ = 0; n_ < 4; ++n_) { \
    bF[n_][0] = *reinterpret_cast<const ix4*>(&ldsb[(DB) + 16384u + bRd + (unsigned)(n_ * 16) * 128u + ks0]); \
    bF[n_][1] = *reinterpret_cast<const ix4*>(&ldsb[(DB) + 16384u + bRd + (unsigned)(n_ * 16) * 128u + ks1]); \
  } \
} while (0)

// stage one 16KB matrix tile: 4 rounds x 32 rows (256 threads x 16B each)
#define STG_M(BASE, P, tau) do { \
  _Pragma("unroll") \
  for (int r_ = 0; r_ < 4; ++r_) \
    __builtin_amdgcn_global_load_lds((const gmem_byte*)((P) + (size_t)(r_ * 32) * K + (size_t)(tau) * 128), \
                                     (lds_byte*)&ldsb[(BASE) + (unsigned)(r_ * 4096) + tOff], 16, 0, 0); \
} while (0)

// 32 MFMA: 4 msub x 4 nsub x chained K=128
#define MM_T() do { \
  _Pragma("unroll") \
  for (int m_ = 0; m_ < 4; ++m_) \
  _Pragma("unroll") \
  for (int n_ = 0; n_ < 4; ++n_) { \
    acc[m_][n_] = __builtin_amdgcn_mfma_i32_16x16x64_i8(aF[m_][0], bF[n_][0], acc[m_][n_], 0, 0, 0); \
    acc[m_][n_] = __builtin_amdgcn_mfma_i32_16x16x64_i8(aF[m_][1], bF[n_][1], acc[m_][n_], 0, 0, 0); \
  } \
} while (0)

__launch_bounds__(256, 2)
__global__ void gemm128_i8_kernel(const char* __restrict__ A, const char* __restrict__ B,
                                  const float* __restrict__ sx, const float* __restrict__ tw,
                                  const float* __restrict__ bias, float* __restrict__ C,
                                  int M, int N, int K) {
  __shared__ __align__(16) unsigned char ldsb[65536];

  const int tid = threadIdx.x;
  const int lane = tid & 63;
  const int w = tid >> 6;       // 0..3
  const int wr = w >> 1;        // m-half 0..1
  const int wc = w & 1;         // n-half 0..1

  // T1: bijective XCD swizzle (MT % 8 == 0 path; MT = M/128).
  const int MT = M >> 7;
  int mt, nt;
  const int bid = blockIdx.x;
  if ((MT & 7) == 0) {
    const int xcd = bid & 7, idx = bid >> 3;
    const int mpx = MT >> 3;
    nt = idx / mpx;
    mt = xcd * mpx + (idx - nt * mpx);
  } else {
    mt = bid % MT;
    nt = bid / MT;
  }
  const int m0 = mt << 7, n0 = nt << 7;

  // ---- staging addressing (linear LDS dest, pre-swizzled global source) ----
  // 256 threads: round covers 32 rows; row = r*32 + (tid>>3), phys slot = tid&7,
  // content slot = phys ^ (row&7) -> scol16 uses (tid>>3)&7 (invariant mod 32).
  const int srow = tid >> 3;            // 0..31
  const int scol16 = (tid & 7) ^ (srow & 7);
  const char* aP = A + (size_t)(m0 + srow) * K + scol16 * 16;
  const char* bP = B + (size_t)(n0 + srow) * K + scol16 * 16;
  const unsigned tOff = (unsigned)tid * 16u;

  // ---- fragment read addressing (verified swizzle fold) ----
  const unsigned fr = lane & 15;
  const unsigned hi16 = (unsigned)lane >> 4;
  const unsigned sw_ = (fr & 7u) << 4;
  const unsigned ks0 = (hi16 * 16u) ^ sw_;          // k-bytes 0..63 chunk
  const unsigned ks1 = (64u + hi16 * 16u) ^ sw_;    // k-bytes 64..127 chunk
  const unsigned aRd = ((unsigned)(wr * 64) + fr) * 128u;   // + msub*16*128
  const unsigned bRd = ((unsigned)(wc * 64) + fr) * 128u;   // + nsub*16*128

  ix4 acc[4][4];
#pragma unroll
  for (int i = 0; i < 4; ++i)
#pragma unroll
    for (int j = 0; j < 4; ++j) acc[i][j] = (ix4){0, 0, 0, 0};

  ix4 aF[4][2], bF[4][2];

  const int NITER = K >> 7;  // K/128 tiles; even, >=4 guarded at launch

  // ---- prologue: tile0 -> buf0, tile1 -> buf1 (16 loads); WAITV(8) ----
  STG_M(0u, aP, 0); STG_M(16384u, bP, 0);
  STG_M(32768u, aP, 1); STG_M(49152u, bP, 1);
  WAITV(8);   // tile0 landed; carry = 8 (tile1)
  BAR();

  for (int it = 0; it < (NITER >> 1) - 1; ++it) {
    const int t = 2 * it;
    // even tile t (buf0)
    RD_T(0u);
    WAITL(0);
    BAR();                       // all waves done reading buf0
    STG_M(0u, aP, t + 2); STG_M(16384u, bP, t + 2);
    SETP(1); MM_T(); SETP(0);
    WAITV(8);                    // drains tile t+1 (buf1)
    BAR();                       // publish buf1
    // odd tile t+1 (buf1)
    RD_T(32768u);
    WAITL(0);
    BAR();
    STG_M(32768u, aP, t + 3); STG_M(49152u, bP, t + 3);
    SETP(1); MM_T(); SETP(0);
    WAITV(8);                    // drains tile t+2 (buf0)
    BAR();                       // publish buf0
  }
  // ---- tail: tiles NITER-2 (buf0), NITER-1 (buf1); no more staging ----
  {
    RD_T(0u);
    WAITV(0);                    // drain tile NITER-1's loads
    BAR();                       // publish buf1
    WAITL(0);
    SETP(1); MM_T(); SETP(0);
    RD_T(32768u);
    WAITL(0);
    SETP(1); MM_T(); SETP(0);
  }

  // ---- epilogue: y = sx[row]*tw[n]*acc + bias ----
  const int row0 = m0 + wr * 64 + ((lane >> 4) << 2);
  const int col0 = n0 + wc * 64 + (lane & 15);
  float sxc[4][4];
#pragma unroll
  for (int m_ = 0; m_ < 4; ++m_) {
    const int rbase = row0 + m_ * 16;
#pragma unroll
    for (int r = 0; r < 4; ++r) sxc[m_][r] = sx[rbase + r];
  }
#pragma unroll
  for (int n_ = 0; n_ < 4; ++n_) {
    const int n = col0 + n_ * 16;
    const float tn = tw[n];
    const float bv = bias[n];
#pragma unroll
    for (int m_ = 0; m_ < 4; ++m_) {
      const int rbase = row0 + m_ * 16;
#pragma unroll
      for (int r = 0; r < 4; ++r)
        C[(size_t)(rbase + r) * N + n] = sxc[m_][r] * tn * (float)acc[m_][n_][r] + bv;
    }
  }
}

// ---------------- fallback path (non-conforming shapes): bf16 two-pass ----------------
__global__ void cvt_x_kernel(const float* __restrict__ x, bf16_t* __restrict__ xb, long n8) {
  const long stride = (long)gridDim.x * blockDim.x;
  for (long i = (long)blockIdx.x * blockDim.x + threadIdx.x; i < n8; i += stride) {
    const float4* p = reinterpret_cast<const float4*>(x + i * 8);
    const float4 f0 = p[0];
    const float4 f1 = p[1];
    bf16x8 o;
    o[0] = (bf16_t)f0.x; o[1] = (bf16_t)f0.y; o[2] = (bf16_t)f0.z; o[3] = (bf16_t)f0.w;
    o[4] = (bf16_t)f1.x; o[5] = (bf16_t)f1.y; o[6] = (bf16_t)f1.z; o[7] = (bf16_t)f1.w;
    *reinterpret_cast<bf16x8*>(xb + i * 8) = o;
  }
}

__global__ void deq_w_kernel(const int* __restrict__ qw, const float* __restrict__ sc,
                             bf16_t* __restrict__ wb, int I, int G) {
  const int n = blockIdx.y;
  const int kb = blockIdx.x * blockDim.x + threadIdx.x;
  const int k = kb * 8;
  if (k >= I) return;
  const float s = sc[(size_t)n * (I / G) + k / G];
  const int4* qp = reinterpret_cast<const int4*>(qw + (size_t)n * I + k);
  const int4 q0 = qp[0];
  const int4 q1 = qp[1];
  bf16x8 o;
  o[0] = (bf16_t)((float)q0.x * s);
  o[1] = (bf16_t)((float)q0.y * s);
  o[2] = (bf16_t)((float)q0.z * s);
  o[3] = (bf16_t)((float)q0.w * s);
  o[4] = (bf16_t)((float)q1.x * s);
  o[5] = (bf16_t)((float)q1.y * s);
  o[6] = (bf16_t)((float)q1.z * s);
  o[7] = (bf16_t)((float)q1.w * s);
  *reinterpret_cast<bf16x8*>(wb + (size_t)n * I + k) = o;
}

#define BM 128
#define BK 32
__launch_bounds__(256)
__global__ void gemm_bt_kernel(const bf16_t* __restrict__ A, const bf16_t* __restrict__ B,
                               const float* __restrict__ bias, float* __restrict__ C,
                               int M, int N, int K) {
  __shared__ __align__(16) bf16_t As[2][BM * BK];
  __shared__ __align__(16) bf16_t Bs[2][BM * BK];
  const int tid = threadIdx.x;
  const int lane = tid & 63;
  const int w = tid >> 6;
  const int wr = w >> 1;
  const int wc = w & 1;
  const int m0 = blockIdx.y * BM;
  const int n0 = blockIdx.x * BM;
  const int srow = lane >> 2;
  const int schunk = lane & 3;
  f32x4 acc[4][4];
  const f32x4 zero = {0.f, 0.f, 0.f, 0.f};
#pragma unroll
  for (int i = 0; i < 4; ++i)
#pragma unroll
    for (int j = 0; j < 4; ++j) acc[i][j] = zero;
  const int nt = K / BK;
  auto stage = [&](int t, int buf) {
    const int k0 = t * BK;
#pragma unroll
    for (int j = 0; j < 2; ++j) {
      const int row = w * 32 + j * 16;
      const bf16_t* ga = A + (size_t)(m0 + row + srow) * K + k0 + schunk * 8;
      __builtin_amdgcn_global_load_lds((const gmem_byte*)ga, (lds_byte*)&As[buf][row * BK], 16, 0, 0);
      const bf16_t* gb = B + (size_t)(n0 + row + srow) * K + k0 + schunk * 8;
      __builtin_amdgcn_global_load_lds((const gmem_byte*)gb, (lds_byte*)&Bs[buf][row * BK], 16, 0, 0);
    }
  };
  auto compute = [&](int buf) {
    bf16x8 af[4], bfr[4];
    const int fr2 = lane & 15;
    const int kc = (lane >> 4) * 8;
#pragma unroll
    for (int i = 0; i < 4; ++i) {
      af[i] = *reinterpret_cast<const bf16x8*>(&As[buf][(wr * 64 + i * 16 + fr2) * BK + kc]);
      bfr[i] = *reinterpret_cast<const bf16x8*>(&Bs[buf][(wc * 64 + i * 16 + fr2) * BK + kc]);
    }
#pragma unroll
    for (int i = 0; i < 4; ++i)
#pragma unroll
      for (int j = 0; j < 4; ++j)
        acc[i][j] = __builtin_amdgcn_mfma_f32_16x16x32_bf16(af[i], bfr[j], acc[i][j], 0, 0, 0);
  };
  stage(0, 0);
  __syncthreads();
  int cur = 0;
  for (int t = 0; t < nt - 1; ++t) {
    stage(t + 1, cur ^ 1);
    compute(cur);
    __syncthreads();
    cur ^= 1;
  }
  compute(cur);
#pragma unroll
  for (int j = 0; j < 4; ++j) {
    const int n = n0 + wc * 64 + j * 16 + (lane & 15);
    const float bv = bias[n];
#pragma unroll
    for (int i = 0; i < 4; ++i) {
      const int mbase = m0 + wr * 64 + i * 16 + (lane >> 4) * 4;
#pragma unroll
      for (int r = 0; r < 4; ++r)
        C[(size_t)(mbase + r) * N + n] = acc[i][j][r] + bv;
    }
  }
}

extern "C" void kernel_launch(void* const* d_in, const int* in_sizes, int n_in,
                              void* d_out, int out_size, void* d_ws, size_t ws_size,
                              hipStream_t stream) {
  const float* x = (const float*)d_in[0];
  const int* qw = (const int*)d_in[1];
  const float* sc = (const float*)d_in[2];
  const float* bias = (const float*)d_in[3];
  float* out = (float*)d_out;

  const long O = in_sizes[3];
  const long I = in_sizes[1] / O;        // 4096
  const long M = in_sizes[0] / I;        // 8192
  const long G = I / (in_sizes[2] / O);  // 128
  const long NG = I / G;

  const size_t i8need = (size_t)(M + O) * I + 4 * (size_t)(M + O);
  const long NITER = I >> 7;
  const bool i8ok = ((M & 127) == 0) && ((O & 127) == 0) && ((I & 127) == 0) &&
                    (G == 128) && (NITER >= 4) && ((NITER & 1) == 0) &&
                    (ws_size >= i8need);
  if (i8ok) {
    char* xq = (char*)d_ws;
    char* wq = xq + (size_t)M * I;
    float* sx = (float*)(wq + (size_t)O * I);
    float* tw = sx + M;
    prep_kernel<<<(unsigned)(M + O), 256, 0, stream>>>(x, (int*)xq, sx, qw, sc, tw,
                                                       (int*)wq, (int)M, (int)I, (int)NG);
    const int nwg = (int)((M >> 7) * (O >> 7));
    gemm128_i8_kernel<<<nwg, 256, 0, stream>>>(xq, wq, sx, tw, bias, out, (int)M, (int)O, (int)I);
  } else {
    bf16_t* xb = (bf16_t*)d_ws;
    bf16_t* wb = xb + (size_t)M * I;
    if (ws_size < (size_t)(M + O) * I * sizeof(bf16_t)) return;
    cvt_x_kernel<<<2048, 256, 0, stream>>>(x, xb, M * I / 8);
    dim3 dgrid((unsigned)((I / 8 + 255) / 256), (unsigned)O);
    deq_w_kernel<<<dgrid, 256, 0, stream>>>(qw, sc, wb, (int)I, (int)G);
    dim3 ggrid((unsigned)(O / BM), (unsigned)(M / BM));
    gemm_bt_kernel<<<ggrid, 256, 0, stream>>>(xb, wb, bias, out, (int)M, (int)O, (int)I);
  }
}

// Round 17
// 483.083 us; speedup vs baseline: 1.0665x; 1.0223x over previous
//
#include <hip/hip_runtime.h>
#include <hip/hip_bf16.h>

// QuantizedLinear: y[M,N] = x[M,K] . W[N,K]^T + bias ; W = int4 * groupscale(G=128)
// Round 16: restore R12 verbatim (best verified: total 479.9us, GEMM 395us).
// i8 GEMM, 128x128 tile, BK=128, 2 blocks/CU antiphase, counted vmcnt, XOR
// swizzle, AGPR i32 acc, epilogue scales, fused prepass. R13 (SGB interleave),
// R14 (64x64 wave-tile), R15 (imm-offset staging) all regressed or broke.

typedef __bf16 bf16_t;
typedef __bf16 bf16x8 __attribute__((ext_vector_type(8)));
typedef float f32x4 __attribute__((ext_vector_type(4)));
typedef int ix4 __attribute__((ext_vector_type(4)));
typedef __attribute__((address_space(3))) unsigned char lds_byte;
typedef __attribute__((address_space(1))) unsigned char gmem_byte;

// ---------------- fused pre-pass: blocks [0,M) = x rows; [M, M+O) = W rows ----------------
__global__ void prep_kernel(const float* __restrict__ x, int* __restrict__ xq,
                            float* __restrict__ sx,
                            const int* __restrict__ qw, const float* __restrict__ sc,
                            float* __restrict__ tw, int* __restrict__ wq,
                            int M, int I, int NG) {
  __shared__ float red[256];
  const int b = blockIdx.x;
  const int t = threadIdx.x;
  if (b < M) {
    const float* row = x + (size_t)b * I;
    float mx = 0.f;
    for (int c = t * 4; c < I; c += 1024) {
      const float4 f = *reinterpret_cast<const float4*>(row + c);
      mx = fmaxf(mx, fmaxf(fmaxf(fabsf(f.x), fabsf(f.y)), fmaxf(fabsf(f.z), fabsf(f.w))));
    }
    red[t] = mx;
    __syncthreads();
#pragma unroll
    for (int s = 128; s > 0; s >>= 1) {
      if (t < s) red[t] = fmaxf(red[t], red[t + s]);
      __syncthreads();
    }
    const float rm = fmaxf(red[0], 1e-30f);
    if (t == 0) sx[b] = rm * (1.f / 127.f);
    const float inv = 127.f / rm;
    int* orow = xq + (size_t)b * (I >> 2);
    for (int c = t * 4; c < I; c += 1024) {
      const float4 f = *reinterpret_cast<const float4*>(row + c);
      const int b0 = (int)rintf(f.x * inv), b1 = (int)rintf(f.y * inv);
      const int b2 = (int)rintf(f.z * inv), b3 = (int)rintf(f.w * inv);
      orow[c >> 2] = (b0 & 255) | ((b1 & 255) << 8) | ((b2 & 255) << 16) | (b3 << 24);
    }
  } else {
    const int n = b - M;
    const float* srow = sc + (size_t)n * NG;
    float mx = 0.f;
    for (int g = t; g < NG; g += 256) mx = fmaxf(mx, srow[g]);
    red[t] = mx;
    __syncthreads();
#pragma unroll
    for (int s = 128; s > 0; s >>= 1) {
      if (t < s) red[t] = fmaxf(red[t], red[t + s]);
      __syncthreads();
    }
    const float tn = fmaxf(red[0], 1e-30f) * (8.f / 127.f);
    if (t == 0) tw[n] = tn;
    const float itn = 1.f / tn;
    const int* qrow = qw + (size_t)n * I;
    int* orow = wq + (size_t)n * (I >> 2);
    for (int k0 = t * 16; k0 < I; k0 += 4096) {
      const float f = srow[k0 >> 7] * itn;
      const int4* p = reinterpret_cast<const int4*>(qrow + k0);
      const int4 q0 = p[0], q1 = p[1], q2 = p[2], q3 = p[3];
      int v[16];
      v[0] = (int)rintf((float)q0.x * f); v[1] = (int)rintf((float)q0.y * f);
      v[2] = (int)rintf((float)q0.z * f); v[3] = (int)rintf((float)q0.w * f);
      v[4] = (int)rintf((float)q1.x * f); v[5] = (int)rintf((float)q1.y * f);
      v[6] = (int)rintf((float)q1.z * f); v[7] = (int)rintf((float)q1.w * f);
      v[8] = (int)rintf((float)q2.x * f); v[9] = (int)rintf((float)q2.y * f);
      v[10] = (int)rintf((float)q2.z * f); v[11] = (int)rintf((float)q2.w * f);
      v[12] = (int)rintf((float)q3.x * f); v[13] = (int)rintf((float)q3.y * f);
      v[14] = (int)rintf((float)q3.z * f); v[15] = (int)rintf((float)q3.w * f);
      int4 o;
      o.x = (v[0] & 255) | ((v[1] & 255) << 8) | ((v[2] & 255) << 16) | (v[3] << 24);
      o.y = (v[4] & 255) | ((v[5] & 255) << 8) | ((v[6] & 255) << 16) | (v[7] << 24);
      o.z = (v[8] & 255) | ((v[9] & 255) << 8) | ((v[10] & 255) << 16) | (v[11] << 24);
      o.w = (v[12] & 255) | ((v[13] & 255) << 8) | ((v[14] & 255) << 16) | (v[15] << 24);
      *reinterpret_cast<int4*>(orow + (k0 >> 2)) = o;
    }
  }
}

// =================== 128x128 8-wave i8 GEMM, 2 blocks/CU ===================
// LDS 64KB: d0.A @0, d0.B @16K, d1.A @32K, d1.B @48K. Tile = 128 rows x 128B
// (128 i8 of K); XOR swizzle 16B-slot ^= (row&7) (verified geometry).
// Waves: 4M x 2N, wave-tile 32x64 -> acc[2][4] (32 i32), aF[2][2], bF[4][2].
// Per tile t (cur = t&1): RD 12x b128; WAITL(0); BAR; STG(cur, t+2) [4 loads];
// MFMA x16; WAITV(4) [drains t+1]; BAR [publish t+1]. Lead 2, never vmcnt 0.

#define WAITV(n) asm volatile("s_waitcnt vmcnt(" #n ")" ::: "memory")
#define WAITL(n) asm volatile("s_waitcnt lgkmcnt(" #n ")" ::: "memory")
#define BAR() __builtin_amdgcn_s_barrier()
#define SETP(n) __builtin_amdgcn_s_setprio(n)

// read full fragment set for the tile in dbuf DB (A @DB, B @DB+16K)
#define RD_T(DB) do { \
  _Pragma("unroll") \
  for (int m_ = 0; m_ < 2; ++m_) { \
    aF[m_][0] = *reinterpret_cast<const ix4*>(&ldsb[(DB) + aRd + (unsigned)(m_ * 16) * 128u + ks0]); \
    aF[m_][1] = *reinterpret_cast<const ix4*>(&ldsb[(DB) + aRd + (unsigned)(m_ * 16) * 128u + ks1]); \
  } \
  _Pragma("unroll") \
  for (int n_ = 0; n_ < 4; ++n_) { \
    bF[n_][0] = *reinterpret_cast<const ix4*>(&ldsb[(DB) + 16384u + bRd + (unsigned)(n_ * 16) * 128u + ks0]); \
    bF[n_][1] = *reinterpret_cast<const ix4*>(&ldsb[(DB) + 16384u + bRd + (unsigned)(n_ * 16) * 128u + ks1]); \
  } \
} while (0)

// stage one 16KB tile-half pair is one matrix: 2 gload_lds (rows 0-63, 64-127)
#define STG(BASE, P, tau) do { \
  __builtin_amdgcn_global_load_lds((const gmem_byte*)((P) + (size_t)(tau) * 128), \
                                   (lds_byte*)&ldsb[(BASE) + wOff], 16, 0, 0); \
  __builtin_amdgcn_global_load_lds((const gmem_byte*)((P) + (size_t)64 * K + (size_t)(tau) * 128), \
                                   (lds_byte*)&ldsb[(BASE) + 8192u + wOff], 16, 0, 0); \
} while (0)

// 16 MFMA: 2 msub x 4 nsub x chained K=128
#define MM_T() do { \
  _Pragma("unroll") \
  for (int m_ = 0; m_ < 2; ++m_) \
  _Pragma("unroll") \
  for (int n_ = 0; n_ < 4; ++n_) { \
    acc[m_][n_] = __builtin_amdgcn_mfma_i32_16x16x64_i8(aF[m_][0], bF[n_][0], acc[m_][n_], 0, 0, 0); \
    acc[m_][n_] = __builtin_amdgcn_mfma_i32_16x16x64_i8(aF[m_][1], bF[n_][1], acc[m_][n_], 0, 0, 0); \
  } \
} while (0)

__launch_bounds__(512, 4)
__global__ void gemm128_i8_kernel(const char* __restrict__ A, const char* __restrict__ B,
                                  const float* __restrict__ sx, const float* __restrict__ tw,
                                  const float* __restrict__ bias, float* __restrict__ C,
                                  int M, int N, int K) {
  __shared__ __align__(16) unsigned char ldsb[65536];

  const int tid = threadIdx.x;
  const int lane = tid & 63;
  const int w = tid >> 6;       // 0..7
  const int wr = w >> 1;        // m-quarter 0..3
  const int wc = w & 1;         // n-half 0..1

  // T1: bijective XCD swizzle (MT % 8 == 0 path; MT = M/128).
  const int MT = M >> 7;
  int mt, nt;
  const int bid = blockIdx.x;
  if ((MT & 7) == 0) {
    const int xcd = bid & 7, idx = bid >> 3;
    const int mpx = MT >> 3;
    nt = idx / mpx;
    mt = xcd * mpx + (idx - nt * mpx);
  } else {
    mt = bid % MT;
    nt = bid / MT;
  }
  const int m0 = mt << 7, n0 = nt << 7;

  // ---- staging addressing (linear LDS dest, pre-swizzled global source) ----
  const int srow8 = lane >> 3;
  const int scol16 = (lane & 7) ^ (srow8 & 7);
  const char* aP = A + (size_t)(m0 + w * 8 + srow8) * K + scol16 * 16;
  const char* bP = B + (size_t)(n0 + w * 8 + srow8) * K + scol16 * 16;
  const unsigned wOff = (unsigned)w * 1024u;

  // ---- fragment read addressing (verified swizzle fold) ----
  const unsigned fr = lane & 15;
  const unsigned hi16 = (unsigned)lane >> 4;
  const unsigned sw_ = (fr & 7u) << 4;
  const unsigned ks0 = (hi16 * 16u) ^ sw_;          // k-bytes 0..63 chunk
  const unsigned ks1 = (64u + hi16 * 16u) ^ sw_;    // k-bytes 64..127 chunk
  const unsigned aRd = ((unsigned)(wr * 32) + fr) * 128u;   // + msub*16*128
  const unsigned bRd = ((unsigned)(wc * 64) + fr) * 128u;   // + nsub*16*128

  ix4 acc[2][4];
#pragma unroll
  for (int i = 0; i < 2; ++i)
#pragma unroll
    for (int j = 0; j < 4; ++j) acc[i][j] = (ix4){0, 0, 0, 0};

  ix4 aF[2][2], bF[4][2];

  const int NITER = K >> 7;  // K/128 tiles; even, >=4 guarded at launch

  // ---- prologue: tile0 -> d0, tile1 -> d1 (8 loads); WAITV(4); publish d0 ----
  STG(0u, aP, 0); STG(16384u, bP, 0);
  STG(32768u, aP, 1); STG(49152u, bP, 1);
  WAITV(4);   // tile0 landed; carry = 4 (tile1)
  BAR();

  for (int it = 0; it < (NITER >> 1) - 1; ++it) {
    const int t = 2 * it;
    // even tile t (d0)
    RD_T(0u);
    WAITL(0);
    BAR();                       // all waves done reading d0
    STG(0u, aP, t + 2); STG(16384u, bP, t + 2);
    SETP(1); MM_T(); SETP(0);
    WAITV(4);                    // drains tile t+1 (d1)
    BAR();                       // publish d1
    // odd tile t+1 (d1)
    RD_T(32768u);
    WAITL(0);
    BAR();
    STG(32768u, aP, t + 3); STG(49152u, bP, t + 3);
    SETP(1); MM_T(); SETP(0);
    WAITV(4);                    // drains tile t+2 (d0)
    BAR();                       // publish d0
  }
  // ---- tail: tiles NITER-2 (d0), NITER-1 (d1); no more staging ----
  {
    RD_T(0u);
    WAITV(0);                    // drain tile NITER-1's loads
    BAR();                       // publish d1
    WAITL(0);
    SETP(1); MM_T(); SETP(0);
    RD_T(32768u);
    WAITL(0);
    SETP(1); MM_T(); SETP(0);
  }

  // ---- epilogue: y = sx[row]*tw[n]*acc + bias ----
  const int row0 = m0 + wr * 32 + ((lane >> 4) << 2);
  const int col0 = n0 + wc * 64 + (lane & 15);
  float sxc[2][4];
#pragma unroll
  for (int m_ = 0; m_ < 2; ++m_) {
    const int rbase = row0 + m_ * 16;
#pragma unroll
    for (int r = 0; r < 4; ++r) sxc[m_][r] = sx[rbase + r];
  }
#pragma unroll
  for (int n_ = 0; n_ < 4; ++n_) {
    const int n = col0 + n_ * 16;
    const float tn = tw[n];
    const float bv = bias[n];
#pragma unroll
    for (int m_ = 0; m_ < 2; ++m_) {
      const int rbase = row0 + m_ * 16;
#pragma unroll
      for (int r = 0; r < 4; ++r)
        C[(size_t)(rbase + r) * N + n] = sxc[m_][r] * tn * (float)acc[m_][n_][r] + bv;
    }
  }
}

// ---------------- fallback path (non-conforming shapes): bf16 two-pass ----------------
__global__ void cvt_x_kernel(const float* __restrict__ x, bf16_t* __restrict__ xb, long n8) {
  const long stride = (long)gridDim.x * blockDim.x;
  for (long i = (long)blockIdx.x * blockDim.x + threadIdx.x; i < n8; i += stride) {
    const float4* p = reinterpret_cast<const float4*>(x + i * 8);
    const float4 f0 = p[0];
    const float4 f1 = p[1];
    bf16x8 o;
    o[0] = (bf16_t)f0.x; o[1] = (bf16_t)f0.y; o[2] = (bf16_t)f0.z; o[3] = (bf16_t)f0.w;
    o[4] = (bf16_t)f1.x; o[5] = (bf16_t)f1.y; o[6] = (bf16_t)f1.z; o[7] = (bf16_t)f1.w;
    *reinterpret_cast<bf16x8*>(xb + i * 8) = o;
  }
}

__global__ void deq_w_kernel(const int* __restrict__ qw, const float* __restrict__ sc,
                             bf16_t* __restrict__ wb, int I, int G) {
  const int n = blockIdx.y;
  const int kb = blockIdx.x * blockDim.x + threadIdx.x;
  const int k = kb * 8;
  if (k >= I) return;
  const float s = sc[(size_t)n * (I / G) + k / G];
  const int4* qp = reinterpret_cast<const int4*>(qw + (size_t)n * I + k);
  const int4 q0 = qp[0];
  const int4 q1 = qp[1];
  bf16x8 o;
  o[0] = (bf16_t)((float)q0.x * s);
  o[1] = (bf16_t)((float)q0.y * s);
  o[2] = (bf16_t)((float)q0.z * s);
  o[3] = (bf16_t)((float)q0.w * s);
  o[4] = (bf16_t)((float)q1.x * s);
  o[5] = (bf16_t)((float)q1.y * s);
  o[6] = (bf16_t)((float)q1.z * s);
  o[7] = (bf16_t)((float)q1.w * s);
  *reinterpret_cast<bf16x8*>(wb + (size_t)n * I + k) = o;
}

#define BM 128
#define BK 32
__launch_bounds__(256)
__global__ void gemm_bt_kernel(const bf16_t* __restrict__ A, const bf16_t* __restrict__ B,
                               const float* __restrict__ bias, float* __restrict__ C,
                               int M, int N, int K) {
  __shared__ __align__(16) bf16_t As[2][BM * BK];
  __shared__ __align__(16) bf16_t Bs[2][BM * BK];
  const int tid = threadIdx.x;
  const int lane = tid & 63;
  const int w = tid >> 6;
  const int wr = w >> 1;
  const int wc = w & 1;
  const int m0 = blockIdx.y * BM;
  const int n0 = blockIdx.x * BM;
  const int srow = lane >> 2;
  const int schunk = lane & 3;
  f32x4 acc[4][4];
  const f32x4 zero = {0.f, 0.f, 0.f, 0.f};
#pragma unroll
  for (int i = 0; i < 4; ++i)
#pragma unroll
    for (int j = 0; j < 4; ++j) acc[i][j] = zero;
  const int nt = K / BK;
  auto stage = [&](int t, int buf) {
    const int k0 = t * BK;
#pragma unroll
    for (int j = 0; j < 2; ++j) {
      const int row = w * 32 + j * 16;
      const bf16_t* ga = A + (size_t)(m0 + row + srow) * K + k0 + schunk * 8;
      __builtin_amdgcn_global_load_lds((const gmem_byte*)ga, (lds_byte*)&As[buf][row * BK], 16, 0, 0);
      const bf16_t* gb = B + (size_t)(n0 + row + srow) * K + k0 + schunk * 8;
      __builtin_amdgcn_global_load_lds((const gmem_byte*)gb, (lds_byte*)&Bs[buf][row * BK], 16, 0, 0);
    }
  };
  auto compute = [&](int buf) {
    bf16x8 af[4], bfr[4];
    const int fr2 = lane & 15;
    const int kc = (lane >> 4) * 8;
#pragma unroll
    for (int i = 0; i < 4; ++i) {
      af[i] = *reinterpret_cast<const bf16x8*>(&As[buf][(wr * 64 + i * 16 + fr2) * BK + kc]);
      bfr[i] = *reinterpret_cast<const bf16x8*>(&Bs[buf][(wc * 64 + i * 16 + fr2) * BK + kc]);
    }
#pragma unroll
    for (int i = 0; i < 4; ++i)
#pragma unroll
      for (int j = 0; j < 4; ++j)
        acc[i][j] = __builtin_amdgcn_mfma_f32_16x16x32_bf16(af[i], bfr[j], acc[i][j], 0, 0, 0);
  };
  stage(0, 0);
  __syncthreads();
  int cur = 0;
  for (int t = 0; t < nt - 1; ++t) {
    stage(t + 1, cur ^ 1);
    compute(cur);
    __syncthreads();
    cur ^= 1;
  }
  compute(cur);
#pragma unroll
  for (int j = 0; j < 4; ++j) {
    const int n = n0 + wc * 64 + j * 16 + (lane & 15);
    const float bv = bias[n];
#pragma unroll
    for (int i = 0; i < 4; ++i) {
      const int mbase = m0 + wr * 64 + i * 16 + (lane >> 4) * 4;
#pragma unroll
      for (int r = 0; r < 4; ++r)
        C[(size_t)(mbase + r) * N + n] = acc[i][j][r] + bv;
    }
  }
}

extern "C" void kernel_launch(void* const* d_in, const int* in_sizes, int n_in,
                              void* d_out, int out_size, void* d_ws, size_t ws_size,
                              hipStream_t stream) {
  const float* x = (const float*)d_in[0];
  const int* qw = (const int*)d_in[1];
  const float* sc = (const float*)d_in[2];
  const float* bias = (const float*)d_in[3];
  float* out = (float*)d_out;

  const long O = in_sizes[3];
  const long I = in_sizes[1] / O;        // 4096
  const long M = in_sizes[0] / I;        // 8192
  const long G = I / (in_sizes[2] / O);  // 128
  const long NG = I / G;

  const size_t i8need = (size_t)(M + O) * I + 4 * (size_t)(M + O);
  const long NITER = I >> 7;
  const bool i8ok = ((M & 127) == 0) && ((O & 127) == 0) && ((I & 127) == 0) &&
                    (G == 128) && (NITER >= 4) && ((NITER & 1) == 0) &&
                    (ws_size >= i8need);
  if (i8ok) {
    char* xq = (char*)d_ws;
    char* wq = xq + (size_t)M * I;
    float* sx = (float*)(wq + (size_t)O * I);
    float* tw = sx + M;
    prep_kernel<<<(unsigned)(M + O), 256, 0, stream>>>(x, (int*)xq, sx, qw, sc, tw,
                                                       (int*)wq, (int)M, (int)I, (int)NG);
    const int nwg = (int)((M >> 7) * (O >> 7));
    gemm128_i8_kernel<<<nwg, 512, 0, stream>>>(xq, wq, sx, tw, bias, out, (int)M, (int)O, (int)I);
  } else {
    bf16_t* xb = (bf16_t*)d_ws;
    bf16_t* wb = xb + (size_t)M * I;
    if (ws_size < (size_t)(M + O) * I * sizeof(bf16_t)) return;
    cvt_x_kernel<<<2048, 256, 0, stream>>>(x, xb, M * I / 8);
    dim3 dgrid((unsigned)((I / 8 + 255) / 256), (unsigned)O);
    deq_w_kernel<<<dgrid, 256, 0, stream>>>(qw, sc, wb, (int)I, (int)G);
    dim3 ggrid((unsigned)(O / BM), (unsigned)(M / BM));
    gemm_bt_kernel<<<ggrid, 256, 0, stream>>>(xb, wb, bias, out, (int)M, (int)O, (int)I);
  }
}